// Round 1
// baseline (679.183 us; speedup 1.0000x reference)
//
#include <hip/hip_runtime.h>

// MHA: B=4 S=2048 D=1024 H=16 DH=64. Full bf16-MFMA pipeline (fp32 accum).
// Threshold is 2% of max|ref| (bf16-tolerant) -> bf16 compute is safe.

#define Bn  4
#define Sn  2048
#define Dn  1024
#define Hn  16
#define DHn 64
#define Mn  (Bn*Sn)          // 8192 rows
#define LDK 72               // LDS row stride (ushorts): 64 + 8 pad -> 2-way-conflict-free

typedef unsigned short u16;
typedef __attribute__((ext_vector_type(8))) short short8;   // 8 x bf16 (4 VGPRs) MFMA A/B frag
typedef __attribute__((ext_vector_type(4))) float f32x4;    // MFMA C/D frag

__device__ __forceinline__ u16 f2bf(float f) {
  unsigned u = __float_as_uint(f);
  return (u16)((u + 0x7FFFu + ((u >> 16) & 1u)) >> 16);   // RNE
}

// ---------------- convert: x (f32) -> xb (bf16), 4 elems/thread ----------------
__global__ __launch_bounds__(256) void k_convert_x(
    const float4* __restrict__ x, ushort4* __restrict__ xb, int n4) {
  int i = blockIdx.x * 256 + threadIdx.x;
  if (i < n4) {
    float4 f = x[i];
    ushort4 o;
    o.x = f2bf(f.x); o.y = f2bf(f.y); o.z = f2bf(f.z); o.w = f2bf(f.w);
    xb[i] = o;
  }
}

// ---- convert+transpose weights to [N][K] bf16 (K contiguous) for GEMM B-operand ----
// WqT/WkT/WvT: row n = h*64+e, col d.  WoT: row n, col k.
__global__ __launch_bounds__(256) void k_convert_w(
    const float* __restrict__ Wq, const float* __restrict__ Wk,
    const float* __restrict__ Wv, const float* __restrict__ Wo,
    u16* __restrict__ WqT, u16* __restrict__ WkT,
    u16* __restrict__ WvT, u16* __restrict__ WoT) {
  int i = blockIdx.x * 256 + threadIdx.x;     // 0 .. 4*2^20-1
  int w = i >> 20;
  int o = i & ((1 << 20) - 1);
  int n = o >> 10, d = o & 1023;
  if (w == 3) {
    WoT[o] = f2bf(Wo[d * Dn + n]);
  } else {
    int h = n >> 6, e = n & 63;
    const float* W = (w == 0) ? Wq : (w == 1) ? Wk : Wv;
    u16*         T = (w == 0) ? WqT : (w == 1) ? WkT : WvT;
    T[o] = f2bf(W[h * (Dn * DHn) + d * DHn + e]);
  }
}

// ---------------- QKV projection GEMM ----------------
// C[8192 x 1024] = xb @ W*T^T (+bias), blockIdx.z selects q/k/v.
// 128x128 tile, 256 thr = 4 waves (2x2 of 64x64), BK=64, 16x16x32 bf16 MFMA.
// q: *0.125, stored [B,H,S,DH]. k: [B,H,S,DH]. v: stored transposed [B,H,DH,S].
__global__ __launch_bounds__(256) void k_gemm_qkv(
    const u16* __restrict__ A, const u16* __restrict__ WqT,
    const u16* __restrict__ WkT, const u16* __restrict__ WvT,
    const float* __restrict__ bq, const float* __restrict__ bk,
    const float* __restrict__ bv,
    u16* __restrict__ qO, u16* __restrict__ kO, u16* __restrict__ vO) {
  const int z = blockIdx.z;
  const u16* BT = (z == 0) ? WqT : (z == 1) ? WkT : WvT;
  const float* bias = (z == 0) ? bq : (z == 1) ? bk : bv;
  const int tile_m = blockIdx.x * 128;
  const int tile_n = blockIdx.y * 128;
  const int K = Dn;

  __shared__ u16 As[128 * LDK];
  __shared__ u16 Bs[128 * LDK];

  const int tid = threadIdx.x;
  const int lane = tid & 63;
  const int wave = tid >> 6;
  const int wm = wave >> 1, wn = wave & 1;
  const int quad = lane >> 4, l16 = lane & 15;

  f32x4 acc[4][4];
#pragma unroll
  for (int i = 0; i < 4; i++)
#pragma unroll
    for (int j = 0; j < 4; j++) acc[i][j] = (f32x4){0.f, 0.f, 0.f, 0.f};

  for (int k0 = 0; k0 < K; k0 += 64) {
#pragma unroll
    for (int r = 0; r < 4; ++r) {           // 1024 x 16B chunks per buffer
      int idx = r * 256 + tid;
      int row = idx >> 3;                   // 8 chunks (128B) per row
      int kq = idx & 7;
      *(uint4*)&As[row * LDK + kq * 8] =
          *(const uint4*)&A[(size_t)(tile_m + row) * K + k0 + kq * 8];
      *(uint4*)&Bs[row * LDK + kq * 8] =
          *(const uint4*)&BT[(size_t)(tile_n + row) * K + k0 + kq * 8];
    }
    __syncthreads();
#pragma unroll
    for (int ks = 0; ks < 2; ++ks) {
      short8 a[4], b[4];
#pragma unroll
      for (int i = 0; i < 4; i++)
        a[i] = *(const short8*)&As[(wm * 64 + i * 16 + l16) * LDK + ks * 32 + quad * 8];
#pragma unroll
      for (int j = 0; j < 4; j++)
        b[j] = *(const short8*)&Bs[(wn * 64 + j * 16 + l16) * LDK + ks * 32 + quad * 8];
#pragma unroll
      for (int i = 0; i < 4; i++)
#pragma unroll
        for (int j = 0; j < 4; j++)
          acc[i][j] = __builtin_amdgcn_mfma_f32_16x16x32_bf16(a[i], b[j], acc[i][j], 0, 0, 0);
    }
    __syncthreads();
  }

  const float scale = (z == 0) ? 0.125f : 1.0f;   // fold 1/sqrt(DH) into q
#pragma unroll
  for (int i = 0; i < 4; i++) {
    const int mbase = tile_m + wm * 64 + i * 16 + quad * 4;
#pragma unroll
    for (int j = 0; j < 4; j++) {
      const int n = tile_n + wn * 64 + j * 16 + l16;
      const float bn = bias[n];
      const int h = n >> 6, e = n & 63;
#pragma unroll
      for (int r = 0; r < 4; r++) {
        const int m = mbase + r;
        const int bb = m >> 11, s = m & 2047;
        const u16 val = f2bf((acc[i][j][r] + bn) * scale);
        if (z == 2)
          vO[((size_t)(bb * Hn + h) * DHn + e) * Sn + s] = val;     // [B,H,DH,S]
        else if (z == 1)
          kO[((size_t)(bb * Hn + h) * Sn + s) * DHn + e] = val;     // [B,H,S,DH]
        else
          qO[((size_t)(bb * Hn + h) * Sn + s) * DHn + e] = val;
      }
    }
  }
}

// ---------------- flash attention ----------------
// grid (S/64, B*H). 4 waves/block, wave owns 16 q-rows, iterates 32-key tiles.
// Online softmax; P transposed C-layout -> A-layout via per-wave LDS.
// ctx written bf16 in concat layout [b, s, h*64+e] for the output GEMM.
__global__ __launch_bounds__(256) void k_attn(
    const u16* __restrict__ qg, const u16* __restrict__ kg,
    const u16* __restrict__ vg, u16* __restrict__ ctx) {
  const int bh = blockIdx.y;
  const int b = bh >> 4, h = bh & 15;
  const int tid = threadIdx.x;
  const int wave = tid >> 6, lane = tid & 63;
  const int quad = lane >> 4, l16 = lane & 15;
  const int qbase = blockIdx.x * 64 + wave * 16;

  const u16* qp = qg + (size_t)bh * Sn * DHn;
  const u16* kp = kg + (size_t)bh * Sn * DHn;
  const u16* vp = vg + (size_t)bh * DHn * Sn;   // [DH][S]

  __shared__ float plds[4][16 * 36];            // per-wave 16x32 P tile, stride 36 (conflict-free)
  float* pl = plds[wave];

  short8 aq[2];                                  // Q A-frags, kept in regs all loop
  aq[0] = *(const short8*)&qp[(size_t)(qbase + l16) * DHn + quad * 8];
  aq[1] = *(const short8*)&qp[(size_t)(qbase + l16) * DHn + 32 + quad * 8];

  f32x4 octx[4];
#pragma unroll
  for (int j = 0; j < 4; j++) octx[j] = (f32x4){0.f, 0.f, 0.f, 0.f};
  float mr[4], lr[4];
#pragma unroll
  for (int r = 0; r < 4; r++) { mr[r] = -1e30f; lr[r] = 0.f; }

  for (int kt = 0; kt < Sn / 32; ++kt) {
    const int key0 = kt * 32;
    // S = q @ k^T (q pre-scaled): two 16x16 C-frags over the 32-key tile
    f32x4 sc0 = (f32x4){0.f, 0.f, 0.f, 0.f}, sc1 = sc0;
    {
      short8 b0 = *(const short8*)&kp[(size_t)(key0 + l16) * DHn + quad * 8];
      short8 b1 = *(const short8*)&kp[(size_t)(key0 + l16) * DHn + 32 + quad * 8];
      sc0 = __builtin_amdgcn_mfma_f32_16x16x32_bf16(aq[0], b0, sc0, 0, 0, 0);
      sc0 = __builtin_amdgcn_mfma_f32_16x16x32_bf16(aq[1], b1, sc0, 0, 0, 0);
      short8 b2 = *(const short8*)&kp[(size_t)(key0 + 16 + l16) * DHn + quad * 8];
      short8 b3 = *(const short8*)&kp[(size_t)(key0 + 16 + l16) * DHn + 32 + quad * 8];
      sc1 = __builtin_amdgcn_mfma_f32_16x16x32_bf16(aq[0], b2, sc1, 0, 0, 0);
      sc1 = __builtin_amdgcn_mfma_f32_16x16x32_bf16(aq[1], b3, sc1, 0, 0, 0);
    }
    // online softmax; C layout: row(q) = quad*4+r, col(key) = l16 (+16 for sc1)
    float mx[4], al[4], p0[4], p1[4], ps[4];
#pragma unroll
    for (int r = 0; r < 4; r++) mx[r] = fmaxf(sc0[r], sc1[r]);
#pragma unroll
    for (int off = 8; off; off >>= 1)
#pragma unroll
      for (int r = 0; r < 4; r++) mx[r] = fmaxf(mx[r], __shfl_xor(mx[r], off));
#pragma unroll
    for (int r = 0; r < 4; r++) {
      float mn = fmaxf(mr[r], mx[r]);
      al[r] = __expf(mr[r] - mn);
      mr[r] = mn;
      p0[r] = __expf(sc0[r] - mn);
      p1[r] = __expf(sc1[r] - mn);
      ps[r] = p0[r] + p1[r];
    }
#pragma unroll
    for (int off = 8; off; off >>= 1)
#pragma unroll
      for (int r = 0; r < 4; r++) ps[r] += __shfl_xor(ps[r], off);
#pragma unroll
    for (int r = 0; r < 4; r++) lr[r] = lr[r] * al[r] + ps[r];
#pragma unroll
    for (int j = 0; j < 4; j++) {
      f32x4 t = octx[j];
#pragma unroll
      for (int r = 0; r < 4; r++) t[r] *= al[r];
      octx[j] = t;
    }
    // P (C layout) -> LDS [qrow][key] -> A-layout frag
#pragma unroll
    for (int r = 0; r < 4; r++) {
      pl[(quad * 4 + r) * 36 + l16] = p0[r];
      pl[(quad * 4 + r) * 36 + 16 + l16] = p1[r];
    }
    __syncthreads();
    float4 pa = *(const float4*)&pl[l16 * 36 + quad * 8];
    float4 pb = *(const float4*)&pl[l16 * 36 + quad * 8 + 4];
    short8 ap;
    ap[0] = (short)f2bf(pa.x); ap[1] = (short)f2bf(pa.y);
    ap[2] = (short)f2bf(pa.z); ap[3] = (short)f2bf(pa.w);
    ap[4] = (short)f2bf(pb.x); ap[5] = (short)f2bf(pb.y);
    ap[6] = (short)f2bf(pb.z); ap[7] = (short)f2bf(pb.w);
    // ctx += P @ V : B-frag from transposed V, contiguous 16B loads
#pragma unroll
    for (int j = 0; j < 4; j++) {
      short8 bv = *(const short8*)&vp[(size_t)(j * 16 + l16) * Sn + key0 + quad * 8];
      octx[j] = __builtin_amdgcn_mfma_f32_16x16x32_bf16(ap, bv, octx[j], 0, 0, 0);
    }
  }

#pragma unroll
  for (int j = 0; j < 4; j++) {
    const int n = h * DHn + j * 16 + l16;
#pragma unroll
    for (int r = 0; r < 4; r++) {
      const int s = qbase + quad * 4 + r;
      ctx[(size_t)(b * Sn + s) * Dn + n] = f2bf(octx[j][r] / lr[r]);
    }
  }
}

// ---------------- output projection GEMM ----------------
__global__ __launch_bounds__(256) void k_gemm_out(
    const u16* __restrict__ A, const u16* __restrict__ WoT,
    const float* __restrict__ bo, float* __restrict__ out) {
  const int tile_m = blockIdx.x * 128;
  const int tile_n = blockIdx.y * 128;
  const int K = Dn;

  __shared__ u16 As[128 * LDK];
  __shared__ u16 Bs[128 * LDK];

  const int tid = threadIdx.x;
  const int lane = tid & 63;
  const int wave = tid >> 6;
  const int wm = wave >> 1, wn = wave & 1;
  const int quad = lane >> 4, l16 = lane & 15;

  f32x4 acc[4][4];
#pragma unroll
  for (int i = 0; i < 4; i++)
#pragma unroll
    for (int j = 0; j < 4; j++) acc[i][j] = (f32x4){0.f, 0.f, 0.f, 0.f};

  for (int k0 = 0; k0 < K; k0 += 64) {
#pragma unroll
    for (int r = 0; r < 4; ++r) {
      int idx = r * 256 + tid;
      int row = idx >> 3;
      int kq = idx & 7;
      *(uint4*)&As[row * LDK + kq * 8] =
          *(const uint4*)&A[(size_t)(tile_m + row) * K + k0 + kq * 8];
      *(uint4*)&Bs[row * LDK + kq * 8] =
          *(const uint4*)&WoT[(size_t)(tile_n + row) * K + k0 + kq * 8];
    }
    __syncthreads();
#pragma unroll
    for (int ks = 0; ks < 2; ++ks) {
      short8 a[4], b[4];
#pragma unroll
      for (int i = 0; i < 4; i++)
        a[i] = *(const short8*)&As[(wm * 64 + i * 16 + l16) * LDK + ks * 32 + quad * 8];
#pragma unroll
      for (int j = 0; j < 4; j++)
        b[j] = *(const short8*)&Bs[(wn * 64 + j * 16 + l16) * LDK + ks * 32 + quad * 8];
#pragma unroll
      for (int i = 0; i < 4; i++)
#pragma unroll
        for (int j = 0; j < 4; j++)
          acc[i][j] = __builtin_amdgcn_mfma_f32_16x16x32_bf16(a[i], b[j], acc[i][j], 0, 0, 0);
    }
    __syncthreads();
  }

#pragma unroll
  for (int i = 0; i < 4; i++) {
    const int mbase = tile_m + wm * 64 + i * 16 + quad * 4;
#pragma unroll
    for (int j = 0; j < 4; j++) {
      const int n = tile_n + wn * 64 + j * 16 + l16;
      const float bn = bo[n];
#pragma unroll
      for (int r = 0; r < 4; r++)
        out[(size_t)(mbase + r) * Dn + n] = acc[i][j][r] + bn;
    }
  }
}

extern "C" void kernel_launch(void* const* d_in, const int* in_sizes, int n_in,
                              void* d_out, int out_size, void* d_ws, size_t ws_size,
                              hipStream_t stream) {
  const float* x  = (const float*)d_in[0];
  const float* Wq = (const float*)d_in[1];
  const float* bq = (const float*)d_in[2];
  const float* Wk = (const float*)d_in[3];
  const float* bk = (const float*)d_in[4];
  const float* Wv = (const float*)d_in[5];
  const float* bv = (const float*)d_in[6];
  const float* Wo = (const float*)d_in[7];
  const float* bo = (const float*)d_in[8];
  float* out = (float*)d_out;

  // workspace carve-up (ctx aliases xb: xb dead after k_gemm_qkv) — ~75.5 MB
  char* ws = (char*)d_ws;
  u16* xb  = (u16*)ws;  ws += (size_t)Mn * Dn * 2;
  u16* WqT = (u16*)ws;  ws += (size_t)Dn * Dn * 2;
  u16* WkT = (u16*)ws;  ws += (size_t)Dn * Dn * 2;
  u16* WvT = (u16*)ws;  ws += (size_t)Dn * Dn * 2;
  u16* WoT = (u16*)ws;  ws += (size_t)Dn * Dn * 2;
  u16* qb  = (u16*)ws;  ws += (size_t)Mn * Dn * 2;
  u16* kb  = (u16*)ws;  ws += (size_t)Mn * Dn * 2;
  u16* vtb = (u16*)ws;  ws += (size_t)Mn * Dn * 2;
  u16* ctx = xb;        // alias

  k_convert_x<<<(Mn * Dn / 4) / 256, 256, 0, stream>>>((const float4*)x, (ushort4*)xb, Mn * Dn / 4);
  k_convert_w<<<(4 * Dn * Dn) / 256, 256, 0, stream>>>(Wq, Wk, Wv, Wo, WqT, WkT, WvT, WoT);

  dim3 g1(Mn / 128, Dn / 128, 3);
  k_gemm_qkv<<<g1, 256, 0, stream>>>(xb, WqT, WkT, WvT, bq, bk, bv, qb, kb, vtb);

  dim3 g2(Sn / 64, Bn * Hn);
  k_attn<<<g2, 256, 0, stream>>>(qb, kb, vtb, ctx);

  dim3 g3(Mn / 128, Dn / 128);
  k_gemm_out<<<g3, 256, 0, stream>>>(ctx, WoT, bo, out);
}